// Round 1
// baseline (176.566 us; speedup 1.0000x reference)
//
#include <hip/hip_runtime.h>

// SparseMaskedLinear: out[b,co] += in[b,ci]*w[e] over 2M edges, B=64, dims 2000.
// Reformulated as dense: W[ci][co] = sum w[e]; out = in[:, :2000] @ W + bias.
// W lives in d_ws (2000*2000*4 = 16 MB) + a 4-byte int64-layout-detect flag.

#define TILE_O 64
#define CHUNK 32
#define SLICES 8

// Detect whether sparse_mask was materialized as int64 (little-endian: every
// odd 32-bit word is the zero high-half, since values are in [0,2000)) or as
// int32 (odd words are random mask values, essentially never all-zero).
__global__ void smw_detect(const unsigned int* __restrict__ m, int* __restrict__ flag) {
    if (blockIdx.x == 0 && threadIdx.x == 0) {
        unsigned int orv = 0u;
        for (int k = 0; k < 64; ++k) orv |= m[2 * k + 1];
        *flag = (orv == 0u) ? 1 : 0;   // 1 => int64 layout
    }
}

__global__ void smw_build(const int* __restrict__ mask, const float* __restrict__ wgt,
                          float* __restrict__ W, const int* __restrict__ flag,
                          int n_edges, int out_f) {
    int e = blockIdx.x * blockDim.x + threadIdx.x;
    if (e >= n_edges) return;
    int ci, co;
    if (*flag) {  // wave-uniform branch
        const long long* m64 = (const long long*)mask;
        ci = (int)m64[2 * (long long)e];
        co = (int)m64[2 * (long long)e + 1];
    } else {
        ci = mask[2 * e];
        co = mask[2 * e + 1];
    }
    atomicAdd(&W[(long long)ci * out_f + co], wgt[e]);
}

__global__ void smw_init_out(float* __restrict__ out, const float* __restrict__ bias,
                             int total, int out_f) {
    int idx = blockIdx.x * blockDim.x + threadIdx.x;
    if (idx < total) out[idx] = bias[idx % out_f];
}

// out[b, o] += sum_i A[b, i] * W[i, o]   for b in [0,64), tile of 64 o's,
// i-chunks strided by SLICES across blockIdx.y. 256 threads = 16x16, each
// thread owns a 4(row)x4(col) micro-tile.
__global__ __launch_bounds__(256) void smw_gemm(
    const float* __restrict__ A, const float* __restrict__ W,
    float* __restrict__ out, int in_features, int out_f, int krows,
    int n_chunks, int Bsz) {
    __shared__ float As[64][CHUNK + 4];   // [b][i], pad 4 -> row stride 144B (16B aligned, <=2-way banks)
    __shared__ float Ws[CHUNK][TILE_O];   // [i][o]

    const int tid = threadIdx.x;
    const int tx = tid & 15;        // col group
    const int ty = tid >> 4;        // row group
    const int o_base = blockIdx.x * TILE_O;

    float acc[4][4] = {};

    for (int c = blockIdx.y; c < n_chunks; c += SLICES) {
        const int i0 = c * CHUNK;
        __syncthreads();
        // Stage A[b][i0+i] -> As[b][i]: 64*32 = 2048 elems, 8 per thread,
        // consecutive lanes load consecutive i (coalesced 128B per row-chunk).
        #pragma unroll
        for (int k = 0; k < 8; ++k) {
            int idx = k * 256 + tid;
            int i = idx & (CHUNK - 1);
            int b = idx >> 5;
            float v = 0.0f;
            int gi = i0 + i;
            if (b < Bsz && gi < in_features) v = A[(long long)b * in_features + gi];
            As[b][i] = v;
        }
        // Stage W[i0+i][o_base+o] -> Ws[i][o]: coalesced 256B rows.
        #pragma unroll
        for (int k = 0; k < 8; ++k) {
            int idx = k * 256 + tid;
            int o = idx & (TILE_O - 1);
            int i = idx >> 6;
            int gi = i0 + i;
            int go = o_base + o;
            Ws[i][o] = (gi < krows && go < out_f) ? W[(long long)gi * out_f + go] : 0.0f;
        }
        __syncthreads();

        #pragma unroll
        for (int i = 0; i < CHUNK; ++i) {
            float4 w4 = *(const float4*)(&Ws[i][tx * 4]);
            float a[4];
            #pragma unroll
            for (int r = 0; r < 4; ++r) a[r] = As[ty * 4 + r][i];
            #pragma unroll
            for (int r = 0; r < 4; ++r) {
                acc[r][0] += a[r] * w4.x;
                acc[r][1] += a[r] * w4.y;
                acc[r][2] += a[r] * w4.z;
                acc[r][3] += a[r] * w4.w;
            }
        }
    }

    // Epilogue: atomic accumulate (SLICES partial sums per cell).
    #pragma unroll
    for (int r = 0; r < 4; ++r) {
        int b = ty * 4 + r;
        if (b >= Bsz) continue;
        #pragma unroll
        for (int cc = 0; cc < 4; ++cc) {
            int o = o_base + tx * 4 + cc;
            if (o < out_f) atomicAdd(&out[(long long)b * out_f + o], acc[r][cc]);
        }
    }
}

extern "C" void kernel_launch(void* const* d_in, const int* in_sizes, int n_in,
                              void* d_out, int out_size, void* d_ws, size_t ws_size,
                              hipStream_t stream) {
    const float* input = (const float*)d_in[0];
    const int*   mask  = (const int*)d_in[1];
    const float* wgt   = (const float*)d_in[2];
    const float* bias  = (const float*)d_in[3];
    float* out = (float*)d_out;

    const int out_f   = in_sizes[3];            // 2000
    const int n_edges = in_sizes[2];            // 2,000,000
    const int Bsz     = out_size / out_f;       // 64
    const int in_features = in_sizes[0] / Bsz;  // 20000
    const int krows   = out_f;                  // input col indices < out_f per problem spec

    float* W = (float*)d_ws;
    size_t wbytes = (size_t)krows * out_f * sizeof(float);  // 16 MB
    int* flag = (int*)((char*)d_ws + wbytes);

    hipMemsetAsync(d_ws, 0, wbytes, stream);
    smw_detect<<<1, 64, 0, stream>>>((const unsigned int*)mask, flag);
    smw_build<<<(n_edges + 255) / 256, 256, 0, stream>>>(mask, wgt, W, flag, n_edges, out_f);
    smw_init_out<<<(out_size + 255) / 256, 256, 0, stream>>>(out, bias, out_size, out_f);

    const int n_chunks = (krows + CHUNK - 1) / CHUNK;
    dim3 grid((out_f + TILE_O - 1) / TILE_O, SLICES);
    smw_gemm<<<grid, 256, 0, stream>>>(input, W, out, in_features, out_f, krows, n_chunks, Bsz);
}

// Round 2
// 130.486 us; speedup vs baseline: 1.3531x; 1.3531x over previous
//
#include <hip/hip_runtime.h>

// SparseMaskedLinear: out[b,co] = bias[co] + sum_e in[b,ci_e]*w_e  (B=64, dims 2000)
// Dense reformulation: W[ci][co] = sum w_e;  out = in[:, :2000] @ W + bias.
// Atomic-free build: bin edges by ci-range (8 rows/bin), then per-bin exclusive
// LDS accumulation -> plain stores. Global f32 atomics measured at only ~20 G/s
// (write-through 32B RMW past L2) -> avoided everywhere.

#define ROWS_PER_BIN 8
#define BIN_CAP 9216          // mean 8000, sigma ~89 -> 13-sigma headroom
#define E_PER 16
#define SEG (256 * E_PER)     // 4096 edges per scatter block

#define TILE_O 64
#define CHUNK 32
#define SLICES 8
#define PSTRIDE 2048

// ---- int64-vs-int32 materialization detect (values < 2000 => int64 high words all 0)
__global__ void smw_detect(const unsigned int* __restrict__ m, int* __restrict__ flag) {
    if (blockIdx.x == 0 && threadIdx.x == 0) {
        unsigned int orv = 0u;
        for (int k = 0; k < 64; ++k) orv |= m[2 * k + 1];
        *flag = (orv == 0u) ? 1 : 0;   // 1 => int64 layout
    }
}

// ---- Phase 1: scatter edges into ci-range bins. One 4096-edge segment per block.
__global__ __launch_bounds__(256) void smw_scatter(
    const int* __restrict__ mask, const float* __restrict__ wgt,
    const int* __restrict__ flag, int* __restrict__ cursor,
    int2* __restrict__ binned, int n_edges, int krows, int nbins) {
    __shared__ int hist[256];
    __shared__ int sbase[256];
    const int tid = threadIdx.x;
    const long long e0 = (long long)blockIdx.x * SEG;
    for (int t = tid; t < nbins; t += 256) hist[t] = 0;
    __syncthreads();
    const bool is64 = (*flag != 0);

    int bin[E_PER]; int rnk[E_PER]; unsigned int key[E_PER]; float wv[E_PER];
    #pragma unroll
    for (int i = 0; i < E_PER; ++i) {
        long long e = e0 + i * 256 + tid;
        bin[i] = -1; rnk[i] = 0; key[i] = 0u; wv[i] = 0.0f;
        if (e < n_edges) {
            int ci, co;
            if (is64) { int4 m = ((const int4*)mask)[e]; ci = m.x; co = m.z; }
            else      { int2 m = ((const int2*)mask)[e]; ci = m.x; co = m.y; }
            if (ci >= 0 && ci < krows) {
                int b = ci >> 3;               // ROWS_PER_BIN = 8
                bin[i] = b;
                key[i] = ((unsigned)(ci & 7) << 16) | (unsigned)co;
                wv[i]  = wgt[e];
                rnk[i] = atomicAdd(&hist[b], 1);   // LDS atomic -> in-segment rank
            }
        }
    }
    __syncthreads();
    for (int t = tid; t < nbins; t += 256) {
        int c = hist[t];
        sbase[t] = c ? atomicAdd(&cursor[t], c) : 0;   // one global int atomic per (bin,block)
    }
    __syncthreads();
    #pragma unroll
    for (int i = 0; i < E_PER; ++i) {
        if (bin[i] >= 0) {
            int pos = sbase[bin[i]] + rnk[i];
            if (pos < BIN_CAP)
                binned[(long long)bin[i] * BIN_CAP + pos] =
                    make_int2((int)key[i], __float_as_int(wv[i]));
        }
    }
}

// ---- Phase 2: per-bin exclusive build of 8 W-rows in LDS, plain stores out.
__global__ __launch_bounds__(256) void smw_bin_build(
    const int2* __restrict__ binned, const int* __restrict__ cursor,
    float* __restrict__ W, int out_f, int krows) {
    __shared__ float tile[ROWS_PER_BIN * 2048];   // out_f <= 2048 guarded on host
    const int tid = threadIdx.x;
    const int bin = blockIdx.x;
    const int tile_elems = ROWS_PER_BIN * out_f;
    for (int t = tid; t < tile_elems; t += 256) tile[t] = 0.0f;
    __syncthreads();
    int n = cursor[bin];
    if (n > BIN_CAP) n = BIN_CAP;
    const int2* src = binned + (long long)bin * BIN_CAP;
    for (int i = tid; i < n; i += 256) {
        int2 rec = src[i];
        unsigned k = (unsigned)rec.x;
        int ci_local = (int)(k >> 16);
        int co = (int)(k & 0xFFFFu);
        atomicAdd(&tile[ci_local * out_f + co], __int_as_float(rec.y));  // ds_add_f32
    }
    __syncthreads();
    for (int r = 0; r < ROWS_PER_BIN; ++r) {
        int row = bin * ROWS_PER_BIN + r;
        if (row >= krows) break;
        float* dst = W + (long long)row * out_f;
        const float* s = tile + r * out_f;
        for (int c = tid; c < out_f; c += 256) dst[c] = s[c];
    }
}

// ---- Phase 3: dense GEMM out_partial[s] = A[:, sliceK] @ W[sliceK, :] (plain stores)
__global__ __launch_bounds__(256) void smw_gemm2(
    const float* __restrict__ A, const float* __restrict__ W,
    float* __restrict__ partial, int in_features, int out_f, int krows,
    int n_chunks, int Bsz) {
    __shared__ float As[64][CHUNK + 4];
    __shared__ float Ws[CHUNK][TILE_O];
    const int tid = threadIdx.x;
    const int tx = tid & 15;
    const int ty = tid >> 4;
    const int o_base = blockIdx.x * TILE_O;

    float acc[4][4] = {};
    for (int c = blockIdx.y; c < n_chunks; c += SLICES) {
        const int i0 = c * CHUNK;
        __syncthreads();
        #pragma unroll
        for (int k = 0; k < 8; ++k) {
            int idx = k * 256 + tid;
            int i = idx & (CHUNK - 1);
            int b = idx >> 5;
            float v = 0.0f;
            int gi = i0 + i;
            if (b < Bsz && gi < in_features) v = A[(long long)b * in_features + gi];
            As[b][i] = v;
        }
        #pragma unroll
        for (int k = 0; k < 8; ++k) {
            int idx = k * 256 + tid;
            int o = idx & (TILE_O - 1);
            int i = idx >> 6;
            int gi = i0 + i;
            int go = o_base + o;
            Ws[i][o] = (gi < krows && go < out_f) ? W[(long long)gi * out_f + go] : 0.0f;
        }
        __syncthreads();
        #pragma unroll
        for (int i = 0; i < CHUNK; ++i) {
            float4 w4 = *(const float4*)(&Ws[i][tx * 4]);
            float a[4];
            #pragma unroll
            for (int r = 0; r < 4; ++r) a[r] = As[ty * 4 + r][i];
            #pragma unroll
            for (int r = 0; r < 4; ++r) {
                acc[r][0] += a[r] * w4.x;
                acc[r][1] += a[r] * w4.y;
                acc[r][2] += a[r] * w4.z;
                acc[r][3] += a[r] * w4.w;
            }
        }
    }
    float* P = partial + (long long)blockIdx.y * Bsz * PSTRIDE;
    #pragma unroll
    for (int r = 0; r < 4; ++r) {
        int b = ty * 4 + r;
        if (b >= Bsz) continue;
        #pragma unroll
        for (int cc = 0; cc < 4; ++cc) {
            int o = o_base + tx * 4 + cc;
            if (o < PSTRIDE) P[(long long)b * PSTRIDE + o] = acc[r][cc];
        }
    }
}

// ---- Phase 4: out = bias + sum_s partial[s]
__global__ void smw_reduce(const float* __restrict__ partial,
                           const float* __restrict__ bias,
                           float* __restrict__ out, int out_f, int Bsz, int total) {
    int idx = blockIdx.x * blockDim.x + threadIdx.x;
    if (idx >= total) return;
    int b = idx / out_f, o = idx - b * out_f;
    float acc = bias[o];
    #pragma unroll
    for (int s = 0; s < SLICES; ++s)
        acc += partial[((long long)s * Bsz + b) * PSTRIDE + o];
    out[idx] = acc;
}

// ================= fallback path (round-1, known-good, needs only 16 MB ws) ==
__global__ void smw_build_fb(const int* __restrict__ mask, const float* __restrict__ wgt,
                             float* __restrict__ W, const int* __restrict__ flag,
                             int n_edges, int out_f) {
    int e = blockIdx.x * blockDim.x + threadIdx.x;
    if (e >= n_edges) return;
    int ci, co;
    if (*flag) {
        const long long* m64 = (const long long*)mask;
        ci = (int)m64[2 * (long long)e];
        co = (int)m64[2 * (long long)e + 1];
    } else {
        ci = mask[2 * e]; co = mask[2 * e + 1];
    }
    atomicAdd(&W[(long long)ci * out_f + co], wgt[e]);
}

__global__ void smw_init_out_fb(float* __restrict__ out, const float* __restrict__ bias,
                                int total, int out_f) {
    int idx = blockIdx.x * blockDim.x + threadIdx.x;
    if (idx < total) out[idx] = bias[idx % out_f];
}

__global__ __launch_bounds__(256) void smw_gemm_fb(
    const float* __restrict__ A, const float* __restrict__ W,
    float* __restrict__ out, int in_features, int out_f, int krows,
    int n_chunks, int Bsz) {
    __shared__ float As[64][CHUNK + 4];
    __shared__ float Ws[CHUNK][TILE_O];
    const int tid = threadIdx.x;
    const int tx = tid & 15;
    const int ty = tid >> 4;
    const int o_base = blockIdx.x * TILE_O;
    float acc[4][4] = {};
    for (int c = blockIdx.y; c < n_chunks; c += SLICES) {
        const int i0 = c * CHUNK;
        __syncthreads();
        #pragma unroll
        for (int k = 0; k < 8; ++k) {
            int idx = k * 256 + tid;
            int i = idx & (CHUNK - 1);
            int b = idx >> 5;
            float v = 0.0f;
            int gi = i0 + i;
            if (b < Bsz && gi < in_features) v = A[(long long)b * in_features + gi];
            As[b][i] = v;
        }
        #pragma unroll
        for (int k = 0; k < 8; ++k) {
            int idx = k * 256 + tid;
            int o = idx & (TILE_O - 1);
            int i = idx >> 6;
            int gi = i0 + i;
            int go = o_base + o;
            Ws[i][o] = (gi < krows && go < out_f) ? W[(long long)gi * out_f + go] : 0.0f;
        }
        __syncthreads();
        #pragma unroll
        for (int i = 0; i < CHUNK; ++i) {
            float4 w4 = *(const float4*)(&Ws[i][tx * 4]);
            float a[4];
            #pragma unroll
            for (int r = 0; r < 4; ++r) a[r] = As[ty * 4 + r][i];
            #pragma unroll
            for (int r = 0; r < 4; ++r) {
                acc[r][0] += a[r] * w4.x;
                acc[r][1] += a[r] * w4.y;
                acc[r][2] += a[r] * w4.z;
                acc[r][3] += a[r] * w4.w;
            }
        }
    }
    #pragma unroll
    for (int r = 0; r < 4; ++r) {
        int b = ty * 4 + r;
        if (b >= Bsz) continue;
        #pragma unroll
        for (int cc = 0; cc < 4; ++cc) {
            int o = o_base + tx * 4 + cc;
            if (o < out_f) atomicAdd(&out[(long long)b * out_f + o], acc[r][cc]);
        }
    }
}

// =============================================================================
static inline size_t align_up(size_t x, size_t a) { return (x + a - 1) & ~(a - 1); }

extern "C" void kernel_launch(void* const* d_in, const int* in_sizes, int n_in,
                              void* d_out, int out_size, void* d_ws, size_t ws_size,
                              hipStream_t stream) {
    const float* input = (const float*)d_in[0];
    const int*   mask  = (const int*)d_in[1];
    const float* wgt   = (const float*)d_in[2];
    const float* bias  = (const float*)d_in[3];
    float* out = (float*)d_out;

    const int out_f   = in_sizes[3];            // 2000
    const int n_edges = in_sizes[2];            // 2,000,000
    const int Bsz     = out_size / out_f;       // 64
    const int in_features = in_sizes[0] / Bsz;  // 20000
    const int krows   = out_f;                  // ci values < out_f per problem spec
    const int nbins   = (krows + ROWS_PER_BIN - 1) / ROWS_PER_BIN;  // 250

    size_t W_bytes      = align_up((size_t)krows * out_f * 4, 1024);
    size_t binned_bytes = align_up((size_t)nbins * BIN_CAP * 8, 1024);
    size_t part_bytes   = align_up((size_t)SLICES * Bsz * PSTRIDE * 4, 1024);
    size_t meta_bytes   = 2048;  // cursor (<=1024) + flag
    size_t need_fast = W_bytes + binned_bytes + part_bytes + meta_bytes;

    char* p = (char*)d_ws;
    float* W      = (float*)p;
    int2*  binned = (int2*)(p + W_bytes);
    float* partial= (float*)(p + W_bytes + binned_bytes);
    int*   cursor = (int*)(p + W_bytes + binned_bytes + part_bytes);
    int*   flag   = cursor + 256;

    const int n_chunks = (krows + CHUNK - 1) / CHUNK;
    const bool fast = (ws_size >= need_fast) && out_f <= 2048 && krows <= 2048 &&
                      nbins <= 256 && Bsz <= 64 && n_edges >= 64;

    if (fast) {
        hipMemsetAsync(cursor, 0, nbins * sizeof(int), stream);
        smw_detect<<<1, 64, 0, stream>>>((const unsigned int*)mask, flag);
        int nseg = (n_edges + SEG - 1) / SEG;                     // 489
        smw_scatter<<<nseg, 256, 0, stream>>>(mask, wgt, flag, cursor, binned,
                                              n_edges, krows, nbins);
        smw_bin_build<<<nbins, 256, 0, stream>>>(binned, cursor, W, out_f, krows);
        dim3 grid((out_f + TILE_O - 1) / TILE_O, SLICES);
        smw_gemm2<<<grid, 256, 0, stream>>>(input, W, partial, in_features, out_f,
                                            krows, n_chunks, Bsz);
        smw_reduce<<<(out_size + 255) / 256, 256, 0, stream>>>(partial, bias, out,
                                                               out_f, Bsz, out_size);
    } else {
        // round-1 known-good path (16 MB + flag)
        int* flag_fb = (int*)(p + (size_t)krows * out_f * 4);
        hipMemsetAsync(d_ws, 0, (size_t)krows * out_f * 4, stream);
        smw_detect<<<1, 64, 0, stream>>>((const unsigned int*)mask, flag_fb);
        smw_build_fb<<<(n_edges + 255) / 256, 256, 0, stream>>>(mask, wgt, W, flag_fb,
                                                                n_edges, out_f);
        smw_init_out_fb<<<(out_size + 255) / 256, 256, 0, stream>>>(out, bias, out_size, out_f);
        dim3 grid((out_f + TILE_O - 1) / TILE_O, SLICES);
        smw_gemm_fb<<<grid, 256, 0, stream>>>(input, W, out, in_features, out_f,
                                              krows, n_chunks, Bsz);
    }
}

// Round 3
// 74.939 us; speedup vs baseline: 2.3561x; 1.7412x over previous
//
#include <hip/hip_runtime.h>

// SparseMaskedLinear: out[b,co] = bias[co] + sum_e in[b,ci_e]*w_e  (B=64, dims 2000)
// Dense reformulation: W[ci][co] = sum w_e;  out = in[:, :2000] @ W + bias.
// Pipeline: detect -> scatter(two-pass bin by ci>>2) -> bin_build(LDS excl.) ->
//           gemm (1024 blocks, full-slice staging) -> reduce.
// No global f32 atomics anywhere (measured ~20 G/s wall). binned/partial share ws.

#define ROWS_PER_BIN 4
#define NB 512                 // hist slots (nbins <= 512)
#define BIN_CAP 4608           // mean 4000, sigma ~63 -> 9.6 sigma headroom
#define SEG2 8192              // edges per scatter block (512 threads, 16/thread/pass)

#define TILE_O 64
#define KS 64
#define SLICES 32
#define PSTRIDE 2048

// ---- int64-vs-int32 materialization detect (values < 2048 => int64 high words all 0)
__global__ void smw_detect(const unsigned int* __restrict__ m, int* __restrict__ flag) {
    if (blockIdx.x == 0 && threadIdx.x == 0) {
        unsigned int orv = 0u;
        for (int k = 0; k < 64; ++k) orv |= m[2 * k + 1];
        *flag = (orv == 0u) ? 1 : 0;   // 1 => int64 layout
    }
}

// ---- Phase 1: two-pass scatter. Pass A: per-block per-bin counts. One global
// int atomic per (bin,block) reserves the range. Pass B: re-read edges, LDS
// rank again (any in-block permutation is fine), write records grouped by bin.
__global__ __launch_bounds__(512) void smw_scatter2(
    const int* __restrict__ mask, const float* __restrict__ wgt,
    const int* __restrict__ flag, int* __restrict__ cursor,
    int2* __restrict__ binned, int n_edges, int krows, int nbins) {
    __shared__ int hist[NB];
    __shared__ int sbase[NB];
    const int tid = threadIdx.x;
    const long long e0 = (long long)blockIdx.x * SEG2;
    for (int t = tid; t < nbins; t += 512) hist[t] = 0;
    __syncthreads();
    const bool is64 = (*flag != 0);

    // pass A: count
    #pragma unroll 4
    for (int t = 0; t < SEG2 / 512; ++t) {
        long long e = e0 + (long long)t * 512 + tid;
        if (e < n_edges) {
            int ci = is64 ? ((const int4*)mask)[e].x : ((const int2*)mask)[e].x;
            if ((unsigned)ci < (unsigned)krows) atomicAdd(&hist[ci >> 2], 1);
        }
    }
    __syncthreads();
    for (int t = tid; t < nbins; t += 512) {
        int c = hist[t];
        sbase[t] = c ? atomicAdd(&cursor[t], c) : 0;
        hist[t] = 0;
    }
    __syncthreads();
    // pass B: rank + write
    #pragma unroll 4
    for (int t = 0; t < SEG2 / 512; ++t) {
        long long e = e0 + (long long)t * 512 + tid;
        if (e < n_edges) {
            int ci, co;
            if (is64) { int4 m = ((const int4*)mask)[e]; ci = m.x; co = m.z; }
            else      { int2 m = ((const int2*)mask)[e]; ci = m.x; co = m.y; }
            if ((unsigned)ci < (unsigned)krows) {
                int b = ci >> 2;
                int r = atomicAdd(&hist[b], 1);
                int pos = sbase[b] + r;
                if (pos < BIN_CAP)
                    binned[(long long)b * BIN_CAP + pos] =
                        make_int2(((ci & 3) << 16) | (co & 0xFFFF), __float_as_int(wgt[e]));
            }
        }
    }
}

// ---- Phase 2: per-bin exclusive build of 4 W-rows in LDS, plain stores out.
__global__ __launch_bounds__(256) void smw_bin_build2(
    const int2* __restrict__ binned, const int* __restrict__ cursor,
    float* __restrict__ W, int out_f, int krows) {
    __shared__ float tile[ROWS_PER_BIN * 2048];   // 32 KB (out_f <= 2048 gated on host)
    const int tid = threadIdx.x;
    const int bin = blockIdx.x;
    const int tile_elems = ROWS_PER_BIN * out_f;
    for (int t = tid; t < tile_elems; t += 256) tile[t] = 0.0f;
    __syncthreads();
    int n = cursor[bin];
    if (n > BIN_CAP) n = BIN_CAP;
    const int2* src = binned + (long long)bin * BIN_CAP;
    for (int i = tid; i < n; i += 256) {
        int2 rec = src[i];
        unsigned k = (unsigned)rec.x;
        atomicAdd(&tile[(int)(k >> 16) * out_f + (int)(k & 0xFFFFu)],
                  __int_as_float(rec.y));   // ds_add_f32, exclusive rows
    }
    __syncthreads();
    #pragma unroll
    for (int r = 0; r < ROWS_PER_BIN; ++r) {
        int row = bin * ROWS_PER_BIN + r;
        if (row >= krows) break;
        float* dst = W + (long long)row * out_f;
        const float* s = tile + r * out_f;
        for (int c = tid; c < out_f; c += 256) dst[c] = s[c];
    }
}

// ---- Phase 3: GEMM partial[s] = A[:, s*KS : s*KS+KS] @ W[slice, o_tile]
// 32 o-tiles x 32 slices = 1024 blocks, full slice staged once (float4), then
// 64 FMA iterations on a 4x4 register micro-tile. Plain float4 stores.
__global__ __launch_bounds__(256) void smw_gemm3(
    const float* __restrict__ A, const float* __restrict__ W,
    float* __restrict__ partial, int in_features, int out_f, int krows, int Bsz) {
    __shared__ float As[64][KS + 4];     // stride 68: ty-stride 272 % 32 = 16 -> 2-way (free)
    __shared__ float Ws[KS][TILE_O];
    const int tid = threadIdx.x;
    const int tx = tid & 15;
    const int ty = tid >> 4;
    const int o_base = blockIdx.x * TILE_O;
    const int k0 = blockIdx.y * KS;

    // stage A: 64 rows x KS floats = 1024 float4, 4 per thread
    #pragma unroll
    for (int t = 0; t < 4; ++t) {
        int idx = t * 256 + tid;
        int b = idx >> 4;
        int c4 = (idx & 15) * 4;
        int gi = k0 + c4;
        float4 v = make_float4(0.f, 0.f, 0.f, 0.f);
        if (b < Bsz) {
            const float* src = A + (long long)b * in_features + gi;
            if (gi + 3 < krows) v = *(const float4*)src;
            else {
                if (gi + 0 < krows) v.x = src[0];
                if (gi + 1 < krows) v.y = src[1];
                if (gi + 2 < krows) v.z = src[2];
                if (gi + 3 < krows) v.w = src[3];
            }
        }
        *(float4*)&As[b][c4] = v;
    }
    // stage W: KS rows x 64 floats = 1024 float4, 4 per thread
    #pragma unroll
    for (int t = 0; t < 4; ++t) {
        int idx = t * 256 + tid;
        int r = idx >> 4;
        int c4 = (idx & 15) * 4;
        int gi = k0 + r;
        int go = o_base + c4;
        float4 v = make_float4(0.f, 0.f, 0.f, 0.f);
        if (gi < krows) {
            const float* src = W + (long long)gi * out_f + go;
            if (go + 3 < out_f) v = *(const float4*)src;
            else {
                if (go + 0 < out_f) v.x = src[0];
                if (go + 1 < out_f) v.y = src[1];
                if (go + 2 < out_f) v.z = src[2];
                if (go + 3 < out_f) v.w = src[3];
            }
        }
        *(float4*)&Ws[r][c4] = v;
    }
    __syncthreads();

    float acc[4][4] = {};
    #pragma unroll 8
    for (int i = 0; i < KS; ++i) {
        float4 w4 = *(const float4*)&Ws[i][tx * 4];
        float a[4];
        #pragma unroll
        for (int r = 0; r < 4; ++r) a[r] = As[ty * 4 + r][i];
        #pragma unroll
        for (int r = 0; r < 4; ++r) {
            acc[r][0] += a[r] * w4.x;
            acc[r][1] += a[r] * w4.y;
            acc[r][2] += a[r] * w4.z;
            acc[r][3] += a[r] * w4.w;
        }
    }

    float* P = partial + (long long)blockIdx.y * 64 * PSTRIDE;
    #pragma unroll
    for (int r = 0; r < 4; ++r) {
        int b = ty * 4 + r;
        if (b < Bsz)
            *(float4*)&P[(long long)b * PSTRIDE + o_base + tx * 4] =
                make_float4(acc[r][0], acc[r][1], acc[r][2], acc[r][3]);
    }
}

// ---- Phase 4: out = bias + sum_s partial[s]  (coalesced scalar lanes)
__global__ void smw_reduce2(const float* __restrict__ partial,
                            const float* __restrict__ bias,
                            float* __restrict__ out, int out_f, int Bsz, int total) {
    int idx = blockIdx.x * blockDim.x + threadIdx.x;
    if (idx >= total) return;
    int b = idx / out_f, o = idx - b * out_f;
    float acc = bias[o];
    #pragma unroll
    for (int s = 0; s < SLICES; ++s)
        acc += partial[((long long)s * 64 + b) * PSTRIDE + o];
    out[idx] = acc;
}

// ================= fallback path (round-1, known-good, needs only 16 MB ws) ==
__global__ void smw_build_fb(const int* __restrict__ mask, const float* __restrict__ wgt,
                             float* __restrict__ W, const int* __restrict__ flag,
                             int n_edges, int out_f) {
    int e = blockIdx.x * blockDim.x + threadIdx.x;
    if (e >= n_edges) return;
    int ci, co;
    if (*flag) {
        const long long* m64 = (const long long*)mask;
        ci = (int)m64[2 * (long long)e];
        co = (int)m64[2 * (long long)e + 1];
    } else {
        ci = mask[2 * e]; co = mask[2 * e + 1];
    }
    atomicAdd(&W[(long long)ci * out_f + co], wgt[e]);
}

__global__ void smw_init_out_fb(float* __restrict__ out, const float* __restrict__ bias,
                                int total, int out_f) {
    int idx = blockIdx.x * blockDim.x + threadIdx.x;
    if (idx < total) out[idx] = bias[idx % out_f];
}

__global__ __launch_bounds__(256) void smw_gemm_fb(
    const float* __restrict__ A, const float* __restrict__ W,
    float* __restrict__ out, int in_features, int out_f, int krows,
    int n_chunks, int Bsz) {
    __shared__ float As[64][36];
    __shared__ float Ws[32][64];
    const int tid = threadIdx.x;
    const int tx = tid & 15;
    const int ty = tid >> 4;
    const int o_base = blockIdx.x * 64;
    float acc[4][4] = {};
    for (int c = blockIdx.y; c < n_chunks; c += 8) {
        const int i0 = c * 32;
        __syncthreads();
        #pragma unroll
        for (int k = 0; k < 8; ++k) {
            int idx = k * 256 + tid;
            int i = idx & 31;
            int b = idx >> 5;
            float v = 0.0f;
            int gi = i0 + i;
            if (b < Bsz && gi < in_features) v = A[(long long)b * in_features + gi];
            As[b][i] = v;
        }
        #pragma unroll
        for (int k = 0; k < 8; ++k) {
            int idx = k * 256 + tid;
            int o = idx & 63;
            int i = idx >> 6;
            int gi = i0 + i;
            int go = o_base + o;
            Ws[i][o] = (gi < krows && go < out_f) ? W[(long long)gi * out_f + go] : 0.0f;
        }
        __syncthreads();
        #pragma unroll
        for (int i = 0; i < 32; ++i) {
            float4 w4 = *(const float4*)(&Ws[i][tx * 4]);
            float a[4];
            #pragma unroll
            for (int r = 0; r < 4; ++r) a[r] = As[ty * 4 + r][i];
            #pragma unroll
            for (int r = 0; r < 4; ++r) {
                acc[r][0] += a[r] * w4.x;
                acc[r][1] += a[r] * w4.y;
                acc[r][2] += a[r] * w4.z;
                acc[r][3] += a[r] * w4.w;
            }
        }
    }
    #pragma unroll
    for (int r = 0; r < 4; ++r) {
        int b = ty * 4 + r;
        if (b >= Bsz) continue;
        #pragma unroll
        for (int cc = 0; cc < 4; ++cc) {
            int o = o_base + tx * 4 + cc;
            if (o < out_f) atomicAdd(&out[(long long)b * out_f + o], acc[r][cc]);
        }
    }
}

// =============================================================================
static inline size_t align_up(size_t x, size_t a) { return (x + a - 1) & ~(a - 1); }

extern "C" void kernel_launch(void* const* d_in, const int* in_sizes, int n_in,
                              void* d_out, int out_size, void* d_ws, size_t ws_size,
                              hipStream_t stream) {
    const float* input = (const float*)d_in[0];
    const int*   mask  = (const int*)d_in[1];
    const float* wgt   = (const float*)d_in[2];
    const float* bias  = (const float*)d_in[3];
    float* out = (float*)d_out;

    const int out_f   = in_sizes[3];            // 2000
    const int n_edges = in_sizes[2];            // 2,000,000
    const int Bsz     = out_size / out_f;       // 64
    const int in_features = in_sizes[0] / Bsz;  // 20000
    const int krows   = out_f;                  // ci values < out_f per problem spec
    const int nbins   = (krows + ROWS_PER_BIN - 1) / ROWS_PER_BIN;  // 500

    size_t W_bytes      = align_up((size_t)krows * out_f * 4, 1024);
    size_t binned_bytes = align_up((size_t)nbins * BIN_CAP * 8, 1024);
    size_t part_bytes   = align_up((size_t)SLICES * 64 * PSTRIDE * 4, 1024);
    size_t union_bytes  = binned_bytes > part_bytes ? binned_bytes : part_bytes;  // overlap!
    size_t meta_bytes   = 4096;
    size_t need_fast = W_bytes + union_bytes + meta_bytes;   // ~34.4 MB (< 37.5 proven)

    char* p = (char*)d_ws;
    float* W      = (float*)p;
    int2*  binned = (int2*)(p + W_bytes);         // dead after bin_build
    float* partial= (float*)(p + W_bytes);        // same region, used after
    int*   cursor = (int*)(p + W_bytes + union_bytes);
    int*   flag   = cursor + NB;

    const bool fast = (ws_size >= need_fast) && out_f <= 2048 && krows <= 2048 &&
                      nbins <= NB && Bsz <= 64 && n_edges >= 1;

    if (fast) {
        hipMemsetAsync(cursor, 0, nbins * sizeof(int), stream);
        smw_detect<<<1, 64, 0, stream>>>((const unsigned int*)mask, flag);
        int nseg = (n_edges + SEG2 - 1) / SEG2;                   // 245
        smw_scatter2<<<nseg, 512, 0, stream>>>(mask, wgt, flag, cursor, binned,
                                               n_edges, krows, nbins);
        smw_bin_build2<<<nbins, 256, 0, stream>>>(binned, cursor, W, out_f, krows);
        dim3 grid((out_f + TILE_O - 1) / TILE_O, SLICES);         // 32 x 32
        smw_gemm3<<<grid, 256, 0, stream>>>(input, W, partial, in_features, out_f,
                                            krows, Bsz);
        smw_reduce2<<<(out_size + 255) / 256, 256, 0, stream>>>(partial, bias, out,
                                                                out_f, Bsz, out_size);
    } else {
        // round-1 known-good path (16 MB + flag)
        int* flag_fb = (int*)(p + (size_t)krows * out_f * 4);
        hipMemsetAsync(d_ws, 0, (size_t)krows * out_f * 4, stream);
        smw_detect<<<1, 64, 0, stream>>>((const unsigned int*)mask, flag_fb);
        smw_build_fb<<<(n_edges + 255) / 256, 256, 0, stream>>>(mask, wgt, W, flag_fb,
                                                                n_edges, out_f);
        smw_init_out_fb<<<(out_size + 255) / 256, 256, 0, stream>>>(out, bias, out_size, out_f);
        const int n_chunks = (krows + 31) / 32;
        dim3 grid((out_f + 63) / 64, 8);
        smw_gemm_fb<<<grid, 256, 0, stream>>>(input, W, out, in_features, out_f,
                                              krows, n_chunks, Bsz);
    }
}